// Round 5
// baseline (223.840 us; speedup 1.0000x reference)
//
#include <hip/hip_runtime.h>
#include <hip/hip_bf16.h>

// Causal flash attention fwd. B=2,H=16,S=2048,D=128, fp32 io, bf16 MFMA.
// R5: LDS-pipe-bound fix — BM=128 (2 m-groups/wave: each LDS read feeds 2 MFMAs),
// permuted K-row storage (S^T C-layout == PV A-layout -> bpermutes deleted),
// double-buffered LDS with one barrier/iter, heavy-first LPT balance.
constexpr int Bb = 2, Hh = 16, Ss = 2048, Dd = 128;
constexpr int BM = 128, BN = 64;
constexpr int NQT = Ss / BM;                     // 16 q-tiles per (b,h)
// 1/sqrt(128) * log2(e): softmax in exp2 domain.
constexpr float SCALE = 0.088388347648318447f * 1.4426950408889634f;

constexpr int KSTRIDE = 272;                    // bytes per K row (64 rows)
constexpr int VSTRIDE = 144;                    // bytes per Vt row (128 rows)
constexpr int KBYTES = BN * KSTRIDE;            // 17408
constexpr int VBYTES = Dd * VSTRIDE;            // 18432

typedef __attribute__((ext_vector_type(8))) short bf16x8;
typedef __attribute__((ext_vector_type(4))) float f32x4;
typedef __attribute__((ext_vector_type(4))) int int4v;

__device__ __forceinline__ unsigned bfbits(float f) {
  union { float f; unsigned u; } v; v.f = f;
  return v.u + 0x7FFFu + ((v.u >> 16) & 1u);    // RNE; bf16 = bits[31:16]
}
__device__ __forceinline__ unsigned pkbf(float lo, float hi) {
#if __has_builtin(__builtin_amdgcn_cvt_pk_bf16_f32)
  typedef __attribute__((ext_vector_type(2))) __bf16 bf16x2;
  bf16x2 r = __builtin_amdgcn_cvt_pk_bf16_f32(lo, hi);
  return __builtin_bit_cast(unsigned, r);
#else
  return __builtin_amdgcn_perm(bfbits(hi), bfbits(lo), 0x07060302u);
#endif
}
__device__ __forceinline__ float exp2fast(float x) {
#if __has_builtin(__builtin_amdgcn_exp2f)
  return __builtin_amdgcn_exp2f(x);
#else
  return exp2f(x);
#endif
}
__device__ __forceinline__ float fcomp(float4 f, int j) {   // j unroll-constant
  return j == 0 ? f.x : (j == 1 ? f.y : (j == 2 ? f.z : f.w));
}
// Store key k at LDS row perm(k) so S^T C-layout == PV A-fragment layout.
__device__ __forceinline__ int permrow(int key) {
  return ((key >> 5) & 1) * 16 + ((key >> 2) & 1) * 32 +
         ((key >> 3) & 3) * 4 + (key & 3);
}

__global__ __launch_bounds__(256, 2)
void fa_fwd_kernel(const float* __restrict__ q, const float* __restrict__ k,
                   const float* __restrict__ v, float* __restrict__ out) {
  __shared__ __align__(16) char Klds[2 * KBYTES];   // K[row'][d] bf16, double-buf
  __shared__ __align__(16) char Vlds[2 * VBYTES];   // Vt[d][key] bf16, double-buf

  const int tid = threadIdx.x;
  const int wave = tid >> 6, lane = tid & 63, quad = lane >> 4, l16 = lane & 15;
  const int bid = blockIdx.x;
  const int bh = bid & 31;
  const int t = (NQT - 1) - (bid >> 5);        // heavy q-tiles dispatched first
  const int last = 2 * t + 1;                  // k-tiles 0..last

  const float* qb = q + (size_t)bh * Ss * Dd;
  const float* kb = k + (size_t)bh * Ss * Dd;
  const float* vb = v + (size_t)bh * Ss * Dd;

  // ---- Q fragments, 2 m-groups: qrow = t*128 + g*64 + wave*16 + l16
  bf16x8 qf[2][4];
  #pragma unroll
  for (int g = 0; g < 2; ++g) {
    const float* qr = qb + (size_t)(t * BM + g * 64 + wave * 16 + l16) * Dd + quad * 8;
    #pragma unroll
    for (int ks = 0; ks < 4; ++ks) {
      float4 a = *(const float4*)(qr + ks * 32);
      float4 b = *(const float4*)(qr + ks * 32 + 4);
      int4v tt = { (int)pkbf(a.x*SCALE, a.y*SCALE), (int)pkbf(a.z*SCALE, a.w*SCALE),
                   (int)pkbf(b.x*SCALE, b.y*SCALE), (int)pkbf(b.z*SCALE, b.w*SCALE) };
      qf[g][ks] = __builtin_bit_cast(bf16x8, tt);
    }
  }

  // ---- staging geometry
  const int krow0 = tid >> 4;            // K: rows krow0+16i (i<4), d-block kblk
  const int kblk  = tid & 15;
  const int vdq = tid >> 3;              // V: d rows 4*vdq..+3, keys vkg*8..+7
  const int vkg = tid & 7;

  float4 ka[4], kc[4];                   // K prefetch (8 fp32 per row)
  float4 vr[8];                          // V prefetch (8 key-rows x 4 d)

  auto load_tiles = [&](int kt) {
    const float* Kg = kb + (size_t)(kt * BN) * Dd + kblk * 8;
    #pragma unroll
    for (int i = 0; i < 4; ++i) {
      ka[i] = *(const float4*)(Kg + (size_t)(krow0 + 16 * i) * Dd);
      kc[i] = *(const float4*)(Kg + (size_t)(krow0 + 16 * i) * Dd + 4);
    }
    const float* Vg = vb + (size_t)(kt * BN + vkg * 8) * Dd + vdq * 4;
    #pragma unroll
    for (int r = 0; r < 8; ++r)
      vr[r] = *(const float4*)(Vg + (size_t)r * Dd);
  };

  auto stage_tiles = [&](int buf) {
    char* Kst = Klds + buf * KBYTES;
    char* Vst = Vlds + buf * VBYTES;
    #pragma unroll
    for (int i = 0; i < 4; ++i) {
      int row = permrow(krow0 + 16 * i);
      int4v tt = { (int)pkbf(ka[i].x, ka[i].y), (int)pkbf(ka[i].z, ka[i].w),
                   (int)pkbf(kc[i].x, kc[i].y), (int)pkbf(kc[i].z, kc[i].w) };
      *(int4v*)(Kst + row * KSTRIDE + kblk * 16) = tt;
    }
    #pragma unroll
    for (int j = 0; j < 4; ++j) {
      int d = vdq * 4 + j;
      int4v tt = { (int)pkbf(fcomp(vr[0], j), fcomp(vr[1], j)),
                   (int)pkbf(fcomp(vr[2], j), fcomp(vr[3], j)),
                   (int)pkbf(fcomp(vr[4], j), fcomp(vr[5], j)),
                   (int)pkbf(fcomp(vr[6], j), fcomp(vr[7], j)) };
      *(int4v*)(Vst + d * VSTRIDE + vkg * 16) = tt;
    }
  };

  f32x4 o[2][8];
  #pragma unroll
  for (int g = 0; g < 2; ++g)
    #pragma unroll
    for (int i = 0; i < 8; ++i) o[g][i] = (f32x4)(0.0f);
  float mrow[2] = {-3.0e38f, -3.0e38f};
  float lrow[2] = {0.0f, 0.0f};

  load_tiles(0);
  stage_tiles(0);

  for (int kt = 0; kt <= last; ++kt) {
    __syncthreads();                     // buf[kt&1] staged; other buf free
    const bool more = kt < last;
    if (more) load_tiles(kt + 1);        // prefetch into regs, no wait

    const char* Krd = Klds + (kt & 1) * KBYTES + l16 * KSTRIDE + quad * 16;
    const char* Vrd = Vlds + (kt & 1) * VBYTES + l16 * VSTRIDE + quad * 16;

    // ---- S^T: acc[g][nt][r] = S[q=l16 of group g][row' = nt*16+quad*4+r]
    f32x4 acc[2][4];
    #pragma unroll
    for (int g = 0; g < 2; ++g)
      #pragma unroll
      for (int nt = 0; nt < 4; ++nt) acc[g][nt] = (f32x4)(0.0f);
    #pragma unroll
    for (int ks = 0; ks < 4; ++ks) {
      #pragma unroll
      for (int nt = 0; nt < 4; ++nt) {
        bf16x8 kf = *(const bf16x8*)(Krd + nt * (16 * KSTRIDE) + ks * 64);
        #pragma unroll
        for (int g = 0; g < 2; ++g)
          acc[g][nt] = __builtin_amdgcn_mfma_f32_16x16x32_bf16(kf, qf[g][ks], acc[g][nt], 0, 0, 0);
      }
    }

    // ---- causal mask (only the top two k-tiles of this q-tile need it)
    if (kt >= 2 * t) {
      #pragma unroll
      for (int g = 0; g < 2; ++g)
        #pragma unroll
        for (int nt = 0; nt < 4; ++nt)
          #pragma unroll
          for (int r = 0; r < 4; ++r) {
            int key = 32 * (nt & 1) + 8 * quad + 4 * (nt >> 1) + r;  // actual key
            if (kt * 64 + key > t * BM + g * 64 + wave * 16 + l16)
              acc[g][nt][r] = -1.0e30f;
          }
    }

    // ---- online softmax per group (base-2); reduce over 4 lanes sharing l16
    #pragma unroll
    for (int g = 0; g < 2; ++g) {
      float mx = acc[g][0][0];
      #pragma unroll
      for (int nt = 0; nt < 4; ++nt)
        #pragma unroll
        for (int r = 0; r < 4; ++r) mx = fmaxf(mx, acc[g][nt][r]);
      mx = fmaxf(mx, __shfl_xor(mx, 16, 64));
      mx = fmaxf(mx, __shfl_xor(mx, 32, 64));
      float mn = fmaxf(mrow[g], mx);
      float alpha = 1.0f;
      if (__any(mx > mrow[g])) {
        alpha = exp2fast(mrow[g] - mn);
        #pragma unroll
        for (int r = 0; r < 4; ++r) {
          int src = (lane & 48) | (quad * 4 + r);
          float ar = __shfl(alpha, src, 64);
          #pragma unroll
          for (int dt = 0; dt < 8; ++dt) o[g][dt][r] *= ar;
        }
      }
      mrow[g] = mn;
      float rs = 0.f;
      #pragma unroll
      for (int nt = 0; nt < 4; ++nt)
        #pragma unroll
        for (int r = 0; r < 4; ++r) {
          float p = exp2fast(acc[g][nt][r] - mn);
          acc[g][nt][r] = p; rs += p;
        }
      rs += __shfl_xor(rs, 16, 64);
      rs += __shfl_xor(rs, 32, 64);
      lrow[g] = lrow[g] * alpha + rs;
    }

    // ---- P A-fragments: pure register pack (permuted K rows line up C->A)
    bf16x8 pf[2][2];
    #pragma unroll
    for (int g = 0; g < 2; ++g)
      #pragma unroll
      for (int ks2 = 0; ks2 < 2; ++ks2) {
        int4v tt = { (int)pkbf(acc[g][ks2][0],     acc[g][ks2][1]),
                     (int)pkbf(acc[g][ks2][2],     acc[g][ks2][3]),
                     (int)pkbf(acc[g][ks2 + 2][0], acc[g][ks2 + 2][1]),
                     (int)pkbf(acc[g][ks2 + 2][2], acc[g][ks2 + 2][3]) };
        pf[g][ks2] = __builtin_bit_cast(bf16x8, tt);
      }

    // ---- O += P V (vf shared across both m-groups)
    #pragma unroll
    for (int ks2 = 0; ks2 < 2; ++ks2) {
      #pragma unroll
      for (int dt = 0; dt < 8; ++dt) {
        bf16x8 vf = *(const bf16x8*)(Vrd + dt * (16 * VSTRIDE) + ks2 * 64);
        #pragma unroll
        for (int g = 0; g < 2; ++g)
          o[g][dt] = __builtin_amdgcn_mfma_f32_16x16x32_bf16(pf[g][ks2], vf, o[g][dt], 0, 0, 0);
      }
    }

    if (more) stage_tiles((kt + 1) & 1);   // write other buffer; vmcnt waits here
  }

  // ---- epilogue: O / l
  #pragma unroll
  for (int g = 0; g < 2; ++g) {
    float linv[4];
    #pragma unroll
    for (int r = 0; r < 4; ++r) {
      int src = (lane & 48) | (quad * 4 + r);
      linv[r] = 1.0f / __shfl(lrow[g], src, 64);
    }
    float* ob = out + ((size_t)bh * Ss + t * BM + g * 64 + wave * 16) * Dd;
    #pragma unroll
    for (int dt = 0; dt < 8; ++dt)
      #pragma unroll
      for (int r = 0; r < 4; ++r)
        ob[(quad * 4 + r) * Dd + dt * 16 + l16] = o[g][dt][r] * linv[r];
  }
}

extern "C" void kernel_launch(void* const* d_in, const int* in_sizes, int n_in,
                              void* d_out, int out_size, void* d_ws, size_t ws_size,
                              hipStream_t stream) {
  const float* q = (const float*)d_in[0];
  const float* k = (const float*)d_in[1];
  const float* v = (const float*)d_in[2];
  float* out = (float*)d_out;
  dim3 grid(Bb * Hh * NQT);   // 512
  dim3 block(256);
  hipLaunchKernelGGL(fa_fwd_kernel, grid, block, 0, stream, q, k, v, out);
}